// Round 3
// baseline (1082.363 us; speedup 1.0000x reference)
//
#include <hip/hip_runtime.h>
#include <math.h>

#define N_PRED   2000000
#define N_OBS    1000000
#define RASU     200000
#define N_IMAGES 2000
#define HMAX     60
#define GRID_    121
#define NGRID3   1771561      // 121^3
#define MC       32
#define NPART    64
#define LOG2PI_D 1.8378770664093453

// Clang-native vector types: __builtin_nontemporal_load/store require these
// (HIP_vector_type structs like float4/int2 are rejected).
typedef float f4 __attribute__((ext_vector_type(4)));
typedef float f2 __attribute__((ext_vector_type(2)));
typedef int   i2 __attribute__((ext_vector_type(2)));

#define NTL(p) __builtin_nontemporal_load(p)

// ---------------- Kernel A0: repack asu into lo16 (u16) + hi2 (2-bit packed) ----------
__global__ __launch_bounds__(256)
void repack_kernel(const int* __restrict__ asu, unsigned short* __restrict__ lo16,
                   unsigned int* __restrict__ hi2)
{
    int w = blockIdx.x * 256 + threadIdx.x;
    int nwords = (NGRID3 + 15) / 16;
    if (w >= nwords) return;
    int base = w * 16;
    unsigned int hibits = 0;
#pragma unroll
    for (int k = 0; k < 16; k++) {
        int idx = base + k;
        int r = (idx < NGRID3) ? asu[idx] : 0;
        if (idx < NGRID3) lo16[idx] = (unsigned short)(r & 0xFFFF);
        hibits |= ((unsigned int)(r >> 16) & 3u) << (2 * k);
    }
    hi2[w] = hibits;
}

// ---------------- Kernel A: softplus, wq = w0*qloc + w1*qs, Z (transposed), KL --------
__global__ __launch_bounds__(256)
void prep_kernel(const float* __restrict__ qloc, const float* __restrict__ qraw,
                 const float* __restrict__ eps, const float* __restrict__ sw,
                 float* __restrict__ Qs, float* __restrict__ wq,
                 float* __restrict__ Z, double* __restrict__ accums, int useZ)
{
    int r = blockIdx.x * 256 + threadIdx.x;
    double klv = 0.0;
    if (r < RASU) {
        float x  = qraw[r];
        float sp = (x > 0.f) ? (x + log1pf(expf(-x))) : log1pf(expf(x));
        float qs = sp + 1e-6f;
        float ql = qloc[r];
        Qs[r] = qs;
        wq[r] = fmaf(sw[0], ql, sw[1] * qs);
        klv = (double)(-logf(qs) + 0.5f * (qs * qs + ql * ql) - 0.5f);
        if (useZ) {
            f4* Zp = (f4*)Z;
#pragma unroll
            for (int c = 0; c < 8; c++) {
                f4 v;
                v.x = fmaf(qs, eps[(size_t)(4 * c + 0) * RASU + r], ql);
                v.y = fmaf(qs, eps[(size_t)(4 * c + 1) * RASU + r], ql);
                v.z = fmaf(qs, eps[(size_t)(4 * c + 2) * RASU + r], ql);
                v.w = fmaf(qs, eps[(size_t)(4 * c + 3) * RASU + r], ql);
                __builtin_nontemporal_store(v, Zp + (size_t)r * 8 + c);
            }
        }
    }
#pragma unroll
    for (int off = 32; off; off >>= 1) klv += __shfl_down(klv, off);
    if ((threadIdx.x & 63) == 0) atomicAdd(&accums[0], klv);
}

// ---------------- Kernel C: one thread per observation -------------------------------
template <int USEZ, int USELOHI>
__global__ __launch_bounds__(256)
void obs_kernel(const int* __restrict__ hkl, const float* __restrict__ I,
                const float* __restrict__ SigI, const int* __restrict__ image_id,
                const float* __restrict__ metadata, const int* __restrict__ asu,
                const unsigned short* __restrict__ lo16, const unsigned int* __restrict__ hi2,
                const float* __restrict__ qloc, const float* __restrict__ Qs,
                const float* __restrict__ wq,
                const float* __restrict__ Z, const float* __restrict__ eps,
                const float* __restrict__ sw, const float* __restrict__ sbp,
                const float* __restrict__ ibias, double* __restrict__ partial)
{
    int o = blockIdx.x * 256 + threadIdx.x;
    if (o >= N_OBS) return;

    float w[9];
#pragma unroll
    for (int j = 0; j < 9; j++) w[j] = sw[j];
    float sb = sbp[0];

    float Iv = NTL(I + o), Sv = NTL(SigI + o);
    float inv  = 1.0f / Sv;
    float logs = logf(Sv);

    int p0 = 2 * o;
    i2 ia = NTL((const i2*)(image_id + p0));
    int img = ia.y;  // numpy last-write-wins scatter: pred 2o+1 wins

    // op-independent per-prediction base of the log-scale
    float basep[2];
    {
        const f2* m0 = (const f2*)(metadata + (size_t)p0 * 5);
        f2 ma = NTL(m0), mb = NTL(m0 + 1), mc_ = NTL(m0 + 2), md = NTL(m0 + 3), me = NTL(m0 + 4);
        float m[10] = {ma.x, ma.y, mb.x, mb.y, mc_.x, mc_.y, md.x, md.y, me.x, me.y};
#pragma unroll
        for (int j = 0; j < 2; j++) {
            float b = w[2] * Iv;
            b = fmaf(w[3], Sv, b);
#pragma unroll
            for (int k = 0; k < 5; k++) b = fmaf(w[4 + k], m[5 * j + k], b);
            basep[j] = b + sb + ibias[j == 0 ? ia.x : ia.y];
        }
    }

    int h[2][3];
    {
        const i2* hp = (const i2*)(hkl + (size_t)p0 * 3);
        i2 h01 = NTL(hp), h23 = NTL(hp + 1), h45 = NTL(hp + 2);
        h[0][0] = h01.x; h[0][1] = h01.y; h[0][2] = h23.x;
        h[1][0] = h23.y; h[1][1] = h45.x; h[1][2] = h45.y;
    }

    int   r[3][2];
    float s[3][2];
    float qv[3][2], qsv[3][2];   // only used by the !USEZ fallback
#pragma unroll
    for (int j = 0; j < 2; j++) {
        int flat[3];
        flat[0] = ((h[j][0] + HMAX) * GRID_ + (h[j][1] + HMAX)) * GRID_ + (h[j][2] + HMAX);
        flat[1] = (NGRID3 - 1) - flat[0];   // inversion op is the exact mirror
        flat[2] = ((h[j][1] + HMAX) * GRID_ + (h[j][0] + HMAX)) * GRID_ + (HMAX - h[j][2]);
#pragma unroll
        for (int op = 0; op < 3; op++) {
            int rr;
            if (USELOHI) {
                int f = flat[op];
                int lo = (int)lo16[f];
                int hi = (int)((hi2[f >> 4] >> ((f & 15) * 2)) & 3u);
                rr = lo | (hi << 16);
            } else {
                rr = asu[flat[op]];
            }
            r[op][j] = rr;
            if (!USEZ) { qv[op][j] = qloc[rr]; qsv[op][j] = Qs[rr]; }
            s[op][j] = expf(basep[j] + wq[rr]);
        }
    }

    float acc[3] = {0.f, 0.f, 0.f};
    if (USEZ) {
        const f4* Zp = (const f4*)Z;
#pragma unroll
        for (int c = 0; c < 8; c++) {
#pragma unroll
            for (int op = 0; op < 3; op++) {
                f4 a = NTL(Zp + (size_t)r[op][0] * 8 + c);
                f4 b = NTL(Zp + (size_t)r[op][1] * 8 + c);
                float s0 = s[op][0], s1 = s[op][1];
                float t;
                t = (fmaf(b.x, s1, a.x * s0) - Iv) * inv; acc[op] = fmaf(t, t, acc[op]);
                t = (fmaf(b.y, s1, a.y * s0) - Iv) * inv; acc[op] = fmaf(t, t, acc[op]);
                t = (fmaf(b.z, s1, a.z * s0) - Iv) * inv; acc[op] = fmaf(t, t, acc[op]);
                t = (fmaf(b.w, s1, a.w * s0) - Iv) * inv; acc[op] = fmaf(t, t, acc[op]);
            }
        }
    } else {
        for (int mc = 0; mc < MC; mc++) {
            const float* ep = eps + (size_t)mc * RASU;
#pragma unroll
            for (int op = 0; op < 3; op++) {
                float z0 = fmaf(qsv[op][0], ep[r[op][0]], qv[op][0]);
                float z1 = fmaf(qsv[op][1], ep[r[op][1]], qv[op][1]);
                float t = (fmaf(z1, s[op][1], z0 * s[op][0]) - Iv) * inv;
                acc[op] = fmaf(t, t, acc[op]);
            }
        }
    }

    double base_ll = -32.0 * ((double)logs + 0.5 * LOG2PI_D);
    int pidx = (int)(blockIdx.x & (NPART - 1));
    double* pp = partial + ((size_t)pidx * N_IMAGES + img) * 3;
#pragma unroll
    for (int op = 0; op < 3; op++) {
        double ll = -0.5 * (double)acc[op] + base_ll;
        atomicAdd(pp + op, ll);
    }
}

// ---------------- Kernel D: per-image reduce over partials, argmax --------------------
__global__ __launch_bounds__(256)
void img_kernel(const double* __restrict__ partial, double* __restrict__ accums,
                float* __restrict__ out)
{
    int i = blockIdx.x * 256 + threadIdx.x;
    if (i >= N_IMAGES) return;
    double l0 = 0, l1 = 0, l2 = 0;
    for (int p = 0; p < NPART; p++) {
        const double* q = partial + ((size_t)p * N_IMAGES + i) * 3;
        l0 += q[0]; l1 += q[1]; l2 += q[2];
    }
    const double ninv = 1.0 / (double)(MC * MC);
    l0 *= ninv; l1 *= ninv; l2 *= ninv;
    int idx = 0; double best = l0;
    if (l1 > best) { best = l1; idx = 1; }
    if (l2 > best) { best = l2; idx = 2; }
    out[1 + i] = (float)idx;
    atomicAdd(&accums[1], best);
}

// ---------------- Kernel E: final ELBO ------------------------------------------------
__global__ void final_kernel(const double* __restrict__ accums, float* __restrict__ out)
{
    double elbo = -(accums[1] / (double)N_IMAGES) + (accums[0] / (double)RASU);
    out[0] = (float)elbo;
}

extern "C" void kernel_launch(void* const* d_in, const int* in_sizes, int n_in,
                              void* d_out, int out_size, void* d_ws, size_t ws_size,
                              hipStream_t stream)
{
    const int*   hkl      = (const int*)  d_in[0];
    const float* I        = (const float*)d_in[1];
    const float* SigI     = (const float*)d_in[2];
    const int*   image_id = (const int*)  d_in[3];
    const float* metadata = (const float*)d_in[4];
    // d_in[5] harmonic_id: structurally arange//2, unused
    const int*   asu      = (const int*)  d_in[6];
    const float* qloc     = (const float*)d_in[7];
    const float* qraw     = (const float*)d_in[8];
    const float* eps      = (const float*)d_in[9];
    const float* sw       = (const float*)d_in[10];
    const float* sb       = (const float*)d_in[11];
    const float* ibias    = (const float*)d_in[12];
    float* out = (float*)d_out;

    char* ws = (char*)d_ws;
    size_t off = 0;
    double* partial = (double*)(ws + off); off += (size_t)NPART * N_IMAGES * 3 * sizeof(double);
    double* accums  = (double*)(ws + off); off += 2 * sizeof(double);
    float*  Qs      = (float*) (ws + off); off += (size_t)RASU * sizeof(float);
    float*  wq      = (float*) (ws + off); off += (size_t)RASU * sizeof(float);
    // lo16/hi2 repacked asu
    unsigned short* lo16 = (unsigned short*)(ws + off); off += (size_t)NGRID3 * sizeof(unsigned short);
    off = (off + 3) & ~(size_t)3;
    unsigned int* hi2 = (unsigned int*)(ws + off); off += (size_t)((NGRID3 + 15) / 16) * sizeof(unsigned int);
    int useLoHi = (off <= ws_size) ? 1 : 0;
    off = (off + 15) & ~(size_t)15;
    float* Z = (float*)(ws + off);
    size_t zbytes = (size_t)RASU * MC * sizeof(float);
    int useZ = (off + zbytes <= ws_size) ? 1 : 0;

    // zero partial bins + the two accumulators (contiguous)
    (void)hipMemsetAsync(partial, 0, (size_t)NPART * N_IMAGES * 3 * sizeof(double) + 2 * sizeof(double), stream);

    if (useLoHi) {
        int nwords = (NGRID3 + 15) / 16;
        repack_kernel<<<(nwords + 255) / 256, 256, 0, stream>>>(asu, lo16, hi2);
    }

    prep_kernel<<<(RASU + 255) / 256, 256, 0, stream>>>(qloc, qraw, eps, sw, Qs, wq, Z, accums, useZ);

    int blocksC = (N_OBS + 255) / 256;
    if (useZ && useLoHi)
        obs_kernel<1,1><<<blocksC, 256, 0, stream>>>(hkl, I, SigI, image_id, metadata, asu, lo16, hi2,
                                                     qloc, Qs, wq, Z, eps, sw, sb, ibias, partial);
    else if (useZ)
        obs_kernel<1,0><<<blocksC, 256, 0, stream>>>(hkl, I, SigI, image_id, metadata, asu, lo16, hi2,
                                                     qloc, Qs, wq, Z, eps, sw, sb, ibias, partial);
    else if (useLoHi)
        obs_kernel<0,1><<<blocksC, 256, 0, stream>>>(hkl, I, SigI, image_id, metadata, asu, lo16, hi2,
                                                     qloc, Qs, wq, Z, eps, sw, sb, ibias, partial);
    else
        obs_kernel<0,0><<<blocksC, 256, 0, stream>>>(hkl, I, SigI, image_id, metadata, asu, lo16, hi2,
                                                     qloc, Qs, wq, Z, eps, sw, sb, ibias, partial);

    img_kernel<<<(N_IMAGES + 255) / 256, 256, 0, stream>>>(partial, accums, out);
    final_kernel<<<1, 1, 0, stream>>>(accums, out);
}

// Round 4
// 557.823 us; speedup vs baseline: 1.9403x; 1.9403x over previous
//
#include <hip/hip_runtime.h>
#include <math.h>

#define N_PRED   2000000
#define N_OBS    1000000
#define RASU     200000
#define N_IMAGES 2000
#define HMAX     60
#define GRID_    121
#define NGRID3   1771561      // 121^3
#define MC       32
#define NPART    64
#define LOG2PI_D 1.8378770664093453

// Clang-native vector types: __builtin_nontemporal_load/store require these
typedef float f4 __attribute__((ext_vector_type(4)));
typedef float f2 __attribute__((ext_vector_type(2)));
typedef int   i2 __attribute__((ext_vector_type(2)));

#define NTL(p) __builtin_nontemporal_load(p)

// ---------------- Kernel A0: repack asu into lo16 (u16) + hi2 (2-bit packed) ----------
__global__ __launch_bounds__(256)
void repack_kernel(const int* __restrict__ asu, unsigned short* __restrict__ lo16,
                   unsigned int* __restrict__ hi2)
{
    int w = blockIdx.x * 256 + threadIdx.x;
    int nwords = (NGRID3 + 15) / 16;
    if (w >= nwords) return;
    int base = w * 16;
    unsigned int hibits = 0;
#pragma unroll
    for (int k = 0; k < 16; k++) {
        int idx = base + k;
        int r = (idx < NGRID3) ? asu[idx] : 0;
        if (idx < NGRID3) lo16[idx] = (unsigned short)(r & 0xFFFF);
        hibits |= ((unsigned int)(r >> 16) & 3u) << (2 * k);
    }
    hi2[w] = hibits;
}

// ---------------- Kernel A: softplus, wq = w0*qloc + w1*qs, Z (transposed), KL --------
__global__ __launch_bounds__(256)
void prep_kernel(const float* __restrict__ qloc, const float* __restrict__ qraw,
                 const float* __restrict__ eps, const float* __restrict__ sw,
                 float* __restrict__ Qs, float* __restrict__ wq,
                 float* __restrict__ Z, double* __restrict__ accums, int useZ)
{
    int r = blockIdx.x * 256 + threadIdx.x;
    double klv = 0.0;
    if (r < RASU) {
        float x  = qraw[r];
        float sp = (x > 0.f) ? (x + log1pf(expf(-x))) : log1pf(expf(x));
        float qs = sp + 1e-6f;
        float ql = qloc[r];
        Qs[r] = qs;
        wq[r] = fmaf(sw[0], ql, sw[1] * qs);
        klv = (double)(-logf(qs) + 0.5f * (qs * qs + ql * ql) - 0.5f);
        if (useZ) {
            f4* Zp = (f4*)Z;
#pragma unroll
            for (int c = 0; c < 8; c++) {
                f4 v;
                v.x = fmaf(qs, eps[(size_t)(4 * c + 0) * RASU + r], ql);
                v.y = fmaf(qs, eps[(size_t)(4 * c + 1) * RASU + r], ql);
                v.z = fmaf(qs, eps[(size_t)(4 * c + 2) * RASU + r], ql);
                v.w = fmaf(qs, eps[(size_t)(4 * c + 3) * RASU + r], ql);
                Zp[(size_t)r * 8 + c] = v;   // normal store: Z is re-read heavily
            }
        }
    }
#pragma unroll
    for (int off = 32; off; off >>= 1) klv += __shfl_down(klv, off);
    if ((threadIdx.x & 63) == 0) atomicAdd(&accums[0], klv);
}

// ---------------- Kernel C: one thread per observation -------------------------------
template <int USEZ, int USELOHI>
__global__ __launch_bounds__(256)
void obs_kernel(const int* __restrict__ hkl, const float* __restrict__ I,
                const float* __restrict__ SigI, const int* __restrict__ image_id,
                const float* __restrict__ metadata, const int* __restrict__ asu,
                const unsigned short* __restrict__ lo16, const unsigned int* __restrict__ hi2,
                const float* __restrict__ qloc, const float* __restrict__ Qs,
                const float* __restrict__ wq,
                const float* __restrict__ Z, const float* __restrict__ eps,
                const float* __restrict__ sw, const float* __restrict__ sbp,
                const float* __restrict__ ibias, double* __restrict__ partial)
{
    int o = blockIdx.x * 256 + threadIdx.x;
    if (o >= N_OBS) return;

    float w[9];
#pragma unroll
    for (int j = 0; j < 9; j++) w[j] = sw[j];
    float sb = sbp[0];

    float Iv = NTL(I + o), Sv = NTL(SigI + o);
    float inv  = 1.0f / Sv;
    float logs = logf(Sv);

    int p0 = 2 * o;
    i2 ia = NTL((const i2*)(image_id + p0));
    int img = ia.y;  // numpy last-write-wins scatter: pred 2o+1 wins

    // op-independent per-prediction base of the log-scale
    float basep[2];
    {
        const f2* m0 = (const f2*)(metadata + (size_t)p0 * 5);
        f2 ma = NTL(m0), mb = NTL(m0 + 1), mc_ = NTL(m0 + 2), md = NTL(m0 + 3), me = NTL(m0 + 4);
        float m[10] = {ma.x, ma.y, mb.x, mb.y, mc_.x, mc_.y, md.x, md.y, me.x, me.y};
#pragma unroll
        for (int j = 0; j < 2; j++) {
            float b = w[2] * Iv;
            b = fmaf(w[3], Sv, b);
#pragma unroll
            for (int k = 0; k < 5; k++) b = fmaf(w[4 + k], m[5 * j + k], b);
            basep[j] = b + sb + ibias[j == 0 ? ia.x : ia.y];
        }
    }

    int h[2][3];
    {
        const i2* hp = (const i2*)(hkl + (size_t)p0 * 3);
        i2 h01 = NTL(hp), h23 = NTL(hp + 1), h45 = NTL(hp + 2);
        h[0][0] = h01.x; h[0][1] = h01.y; h[0][2] = h23.x;
        h[1][0] = h23.y; h[1][1] = h45.x; h[1][2] = h45.y;
    }

    int   r[3][2];
    float s[3][2];
    float qv[3][2], qsv[3][2];   // only used by the !USEZ fallback
#pragma unroll
    for (int j = 0; j < 2; j++) {
        int flat[3];
        flat[0] = ((h[j][0] + HMAX) * GRID_ + (h[j][1] + HMAX)) * GRID_ + (h[j][2] + HMAX);
        flat[1] = (NGRID3 - 1) - flat[0];   // inversion op is the exact mirror
        flat[2] = ((h[j][1] + HMAX) * GRID_ + (h[j][0] + HMAX)) * GRID_ + (HMAX - h[j][2]);
#pragma unroll
        for (int op = 0; op < 3; op++) {
            int rr;
            if (USELOHI) {
                int f = flat[op];
                int lo = (int)lo16[f];
                int hi = (int)((hi2[f >> 4] >> ((f & 15) * 2)) & 3u);
                rr = lo | (hi << 16);
            } else {
                rr = asu[flat[op]];
            }
            r[op][j] = rr;
            if (!USEZ) { qv[op][j] = qloc[rr]; qsv[op][j] = Qs[rr]; }
            s[op][j] = expf(basep[j] + wq[rr]);
        }
    }

    float acc[3] = {0.f, 0.f, 0.f};
    if (USEZ) {
        const f4* Zp = (const f4*)Z;
        // op-OUTER, c-inner: both 128B rows of this op are consumed completely
        // while hot (2 live lines/thread -> L1-resident), no cross-op refetch.
#pragma unroll
        for (int op = 0; op < 3; op++) {
            const f4* pa = Zp + (size_t)r[op][0] * 8;
            const f4* pb = Zp + (size_t)r[op][1] * 8;
            float s0 = s[op][0], s1 = s[op][1];
            float a3 = 0.f;
#pragma unroll
            for (int c = 0; c < 8; c++) {
                f4 a = pa[c];
                f4 b = pb[c];
                float t;
                t = (fmaf(b.x, s1, a.x * s0) - Iv) * inv; a3 = fmaf(t, t, a3);
                t = (fmaf(b.y, s1, a.y * s0) - Iv) * inv; a3 = fmaf(t, t, a3);
                t = (fmaf(b.z, s1, a.z * s0) - Iv) * inv; a3 = fmaf(t, t, a3);
                t = (fmaf(b.w, s1, a.w * s0) - Iv) * inv; a3 = fmaf(t, t, a3);
            }
            acc[op] = a3;
        }
    } else {
        for (int mc = 0; mc < MC; mc++) {
            const float* ep = eps + (size_t)mc * RASU;
#pragma unroll
            for (int op = 0; op < 3; op++) {
                float z0 = fmaf(qsv[op][0], ep[r[op][0]], qv[op][0]);
                float z1 = fmaf(qsv[op][1], ep[r[op][1]], qv[op][1]);
                float t = (fmaf(z1, s[op][1], z0 * s[op][0]) - Iv) * inv;
                acc[op] = fmaf(t, t, acc[op]);
            }
        }
    }

    double base_ll = -32.0 * ((double)logs + 0.5 * LOG2PI_D);
    int pidx = (int)(blockIdx.x & (NPART - 1));
    double* pp = partial + ((size_t)pidx * N_IMAGES + img) * 3;
#pragma unroll
    for (int op = 0; op < 3; op++) {
        double ll = -0.5 * (double)acc[op] + base_ll;
        atomicAdd(pp + op, ll);
    }
}

// ---------------- Kernel D: per-image reduce over partials, argmax --------------------
__global__ __launch_bounds__(256)
void img_kernel(const double* __restrict__ partial, double* __restrict__ accums,
                float* __restrict__ out)
{
    int i = blockIdx.x * 256 + threadIdx.x;
    if (i >= N_IMAGES) return;
    double l0 = 0, l1 = 0, l2 = 0;
    for (int p = 0; p < NPART; p++) {
        const double* q = partial + ((size_t)p * N_IMAGES + i) * 3;
        l0 += q[0]; l1 += q[1]; l2 += q[2];
    }
    const double ninv = 1.0 / (double)(MC * MC);
    l0 *= ninv; l1 *= ninv; l2 *= ninv;
    int idx = 0; double best = l0;
    if (l1 > best) { best = l1; idx = 1; }
    if (l2 > best) { best = l2; idx = 2; }
    out[1 + i] = (float)idx;
    atomicAdd(&accums[1], best);
}

// ---------------- Kernel E: final ELBO ------------------------------------------------
__global__ void final_kernel(const double* __restrict__ accums, float* __restrict__ out)
{
    double elbo = -(accums[1] / (double)N_IMAGES) + (accums[0] / (double)RASU);
    out[0] = (float)elbo;
}

extern "C" void kernel_launch(void* const* d_in, const int* in_sizes, int n_in,
                              void* d_out, int out_size, void* d_ws, size_t ws_size,
                              hipStream_t stream)
{
    const int*   hkl      = (const int*)  d_in[0];
    const float* I        = (const float*)d_in[1];
    const float* SigI     = (const float*)d_in[2];
    const int*   image_id = (const int*)  d_in[3];
    const float* metadata = (const float*)d_in[4];
    // d_in[5] harmonic_id: structurally arange//2, unused
    const int*   asu      = (const int*)  d_in[6];
    const float* qloc     = (const float*)d_in[7];
    const float* qraw     = (const float*)d_in[8];
    const float* eps      = (const float*)d_in[9];
    const float* sw       = (const float*)d_in[10];
    const float* sb       = (const float*)d_in[11];
    const float* ibias    = (const float*)d_in[12];
    float* out = (float*)d_out;

    char* ws = (char*)d_ws;
    size_t off = 0;
    double* partial = (double*)(ws + off); off += (size_t)NPART * N_IMAGES * 3 * sizeof(double);
    double* accums  = (double*)(ws + off); off += 2 * sizeof(double);
    float*  Qs      = (float*) (ws + off); off += (size_t)RASU * sizeof(float);
    float*  wq      = (float*) (ws + off); off += (size_t)RASU * sizeof(float);
    unsigned short* lo16 = (unsigned short*)(ws + off); off += (size_t)NGRID3 * sizeof(unsigned short);
    off = (off + 3) & ~(size_t)3;
    unsigned int* hi2 = (unsigned int*)(ws + off); off += (size_t)((NGRID3 + 15) / 16) * sizeof(unsigned int);
    int useLoHi = (off <= ws_size) ? 1 : 0;
    off = (off + 15) & ~(size_t)15;
    float* Z = (float*)(ws + off);
    size_t zbytes = (size_t)RASU * MC * sizeof(float);
    int useZ = (off + zbytes <= ws_size) ? 1 : 0;

    (void)hipMemsetAsync(partial, 0, (size_t)NPART * N_IMAGES * 3 * sizeof(double) + 2 * sizeof(double), stream);

    if (useLoHi) {
        int nwords = (NGRID3 + 15) / 16;
        repack_kernel<<<(nwords + 255) / 256, 256, 0, stream>>>(asu, lo16, hi2);
    }

    prep_kernel<<<(RASU + 255) / 256, 256, 0, stream>>>(qloc, qraw, eps, sw, Qs, wq, Z, accums, useZ);

    int blocksC = (N_OBS + 255) / 256;
    if (useZ && useLoHi)
        obs_kernel<1,1><<<blocksC, 256, 0, stream>>>(hkl, I, SigI, image_id, metadata, asu, lo16, hi2,
                                                     qloc, Qs, wq, Z, eps, sw, sb, ibias, partial);
    else if (useZ)
        obs_kernel<1,0><<<blocksC, 256, 0, stream>>>(hkl, I, SigI, image_id, metadata, asu, lo16, hi2,
                                                     qloc, Qs, wq, Z, eps, sw, sb, ibias, partial);
    else if (useLoHi)
        obs_kernel<0,1><<<blocksC, 256, 0, stream>>>(hkl, I, SigI, image_id, metadata, asu, lo16, hi2,
                                                     qloc, Qs, wq, Z, eps, sw, sb, ibias, partial);
    else
        obs_kernel<0,0><<<blocksC, 256, 0, stream>>>(hkl, I, SigI, image_id, metadata, asu, lo16, hi2,
                                                     qloc, Qs, wq, Z, eps, sw, sb, ibias, partial);

    img_kernel<<<(N_IMAGES + 255) / 256, 256, 0, stream>>>(partial, accums, out);
    final_kernel<<<1, 1, 0, stream>>>(accums, out);
}